// Round 4
// baseline (161.343 us; speedup 1.0000x reference)
//
#include <hip/hip_runtime.h>

// LSTM: B=16384 sequences, T=1024 steps, I=1, H=2, C=4.
// 1 thread per batch element; the whole recurrence lives in registers.
// Gate order (PyTorch): i (k=0,1), f (k=2,3), g (k=4,5), o (k=6,7).
//
// Nonlinearity formulation (merged reciprocals, raw v_exp_f32 / v_rcp_f32):
//   E_k = exp2(s_k * pre_k),  s_k = -log2(e) for i,f,o ;  +2*log2(e) for g
//   c' = [c*(1+Ei)(Eg+1) + (Eg-1)(1+Ef)] / [(1+Ef)(1+Ei)(Eg+1)]     (1 rcp)
//   h' = (Ec-1) / [(1+Eo)(Ec+1)],  Ec = exp2(clamp(2log2e * c', +-30)) (1 rcp)
// => 10 exp2 + 4 rcp per element-step (vs 20 trans naive).

static __device__ __forceinline__ float fast_exp2(float x) { return __builtin_amdgcn_exp2f(x); }
static __device__ __forceinline__ float fast_rcp(float x)  { return __builtin_amdgcn_rcpf(x); }

#define SIG_SCALE  (-1.4426950408889634f)  // -log2(e)
#define TANH_SCALE ( 2.8853900817779268f)  // 2*log2(e)

__global__ __launch_bounds__(64, 1) void lstm_fused(
    const float* __restrict__ x,      // [B, T, 1]
    const float* __restrict__ W_ih,   // [8, 1]
    const float* __restrict__ W_hh,   // [8, 2]
    const float* __restrict__ b_ih,   // [8]
    const float* __restrict__ b_hh,   // [8]
    const float* __restrict__ W_fc,   // [4, 2]
    const float* __restrict__ b_fc,   // [4]
    float* __restrict__ out,          // [B, 4]
    int T)
{
    const int b = blockIdx.x * 64 + threadIdx.x;

    // Fold the exp2 scale factors into the weights once per thread
    // (uniform loads -> scalar cache; amortized over 1024 steps).
    float wih[8], wh0[8], wh1[8], bb[8];
#pragma unroll
    for (int k = 0; k < 8; ++k) {
        const float s = (k == 4 || k == 5) ? TANH_SCALE : SIG_SCALE;
        wih[k] = s * W_ih[k];
        wh0[k] = s * W_hh[2 * k + 0];
        wh1[k] = s * W_hh[2 * k + 1];
        bb[k]  = s * (b_ih[k] + b_hh[k]);
    }

    float h0 = 0.f, h1 = 0.f, c0 = 0.f, c1 = 0.f;

    const float4* xv = reinterpret_cast<const float4*>(x + (size_t)b * (size_t)T);
    const int nt4 = T >> 2;

    for (int t4 = 0; t4 < nt4; ++t4) {
        const float4 xq = xv[t4];
        float xs[4] = {xq.x, xq.y, xq.z, xq.w};

        // x-terms for all 4 timesteps up front: h-independent ILP the
        // scheduler can overlap with the recurrent chain.
        float xterm[4][8];
#pragma unroll
        for (int u = 0; u < 4; ++u)
#pragma unroll
            for (int k = 0; k < 8; ++k)
                xterm[u][k] = fmaf(xs[u], wih[k], bb[k]);

#pragma unroll
        for (int u = 0; u < 4; ++u) {
            float E[8];
#pragma unroll
            for (int k = 0; k < 8; ++k) {
                const float pre = fmaf(wh0[k], h0, fmaf(wh1[k], h1, xterm[u][k]));
                E[k] = fast_exp2(pre);
            }
#pragma unroll
            for (int j = 0; j < 2; ++j) {
                const float Ei = E[0 + j], Ef = E[2 + j], Eg = E[4 + j], Eo = E[6 + j];
                float c = j ? c1 : c0;

                const float F   = 1.f + Ef;
                const float Gp  = 1.f + Eg;
                const float P   = fmaf(Ei, Gp, Gp);            // (1+Ei)(1+Eg)
                const float GmF = fmaf(Eg, F, -F);             // (Eg-1)(1+Ef)
                const float num = fmaf(c, P, GmF);
                const float den = F * P;
                c = num * fast_rcp(den);

                const float a  = fminf(fmaxf(TANH_SCALE * c, -30.f), 30.f);
                const float Ec = fast_exp2(a);
                const float dh = (1.f + Eo) * (Ec + 1.f);
                const float r  = fast_rcp(dh);
                const float h  = fmaf(Ec, r, -r);              // (Ec-1)/dh

                if (j) { c1 = c; h1 = h; } else { c0 = c; h0 = h; }
            }
        }
    }

    // Final FC: out[b, :] = h @ W_fc^T + b_fc   (C=4, H=2)
    const float o0 = fmaf(W_fc[0], h0, fmaf(W_fc[1], h1, b_fc[0]));
    const float o1 = fmaf(W_fc[2], h0, fmaf(W_fc[3], h1, b_fc[1]));
    const float o2 = fmaf(W_fc[4], h0, fmaf(W_fc[5], h1, b_fc[2]));
    const float o3 = fmaf(W_fc[6], h0, fmaf(W_fc[7], h1, b_fc[3]));
    float4 r4; r4.x = o0; r4.y = o1; r4.z = o2; r4.w = o3;
    reinterpret_cast<float4*>(out)[b] = r4;
}

extern "C" void kernel_launch(void* const* d_in, const int* in_sizes, int n_in,
                              void* d_out, int out_size, void* d_ws, size_t ws_size,
                              hipStream_t stream) {
    const float* x    = (const float*)d_in[0];
    const float* W_ih = (const float*)d_in[1];
    const float* W_hh = (const float*)d_in[2];
    const float* b_ih = (const float*)d_in[3];
    const float* b_hh = (const float*)d_in[4];
    const float* W_fc = (const float*)d_in[5];
    const float* b_fc = (const float*)d_in[6];
    float* out = (float*)d_out;

    const int T = 1024;
    const int B = in_sizes[0] / T;   // I == 1

    dim3 block(64);
    dim3 grid(B / 64);               // B = 16384 -> 256 blocks, 1 wave/CU
    lstm_fused<<<grid, block, 0, stream>>>(x, W_ih, W_hh, b_ih, b_hh, W_fc, b_fc, out, T);
}

// Round 5
// 129.688 us; speedup vs baseline: 1.2441x; 1.2441x over previous
//
#include <hip/hip_runtime.h>

// LSTM: B=16384, T=1024, I=1, H=2, C=4.
// 2 lanes per batch element: lane (2e+j) owns hidden unit j of element e.
// All gate math for unit j is lane-local (4 exp2 + 2 rcp per step/lane);
// the recurrent cross-unit h is exchanged with one __shfl_xor (quad_perm DPP).
// 32768 threads = 512 waves -> 2 waves/CU (2 SIMDs busy) vs 1 before,
// and per-wave instructions per step roughly halve: ~2x issue capacity.
//
// Gate rows (PyTorch order) in the [8]-row weight tensors:
//   i: rows 0,1   f: rows 2,3   g: rows 4,5   o: rows 6,7
// Merged-reciprocal activations (exp2-scale folded into the weights):
//   E_k = exp2(s_k*pre_k), s_k = -log2(e) for i,f,o ; +2*log2(e) for g
//   c' = [c*(1+Ei)(1+Eg) + (Eg-1)(1+Ef)] / [(1+Ef)(1+Ei)(1+Eg)]   (1 rcp)
//   h' = (Ec-1)/[(1+Eo)(Ec+1)], Ec = exp2(med3(2log2e*c', -30, 30)) (1 rcp)

typedef float f32x2 __attribute__((ext_vector_type(2)));

static __device__ __forceinline__ float fast_exp2(float x) { return __builtin_amdgcn_exp2f(x); }
static __device__ __forceinline__ float fast_rcp(float x)  { return __builtin_amdgcn_rcpf(x); }

#define SIG_SCALE  (-1.4426950408889634f)  // -log2(e)
#define TANH_SCALE ( 2.8853900817779268f)  // 2*log2(e)

__global__ __launch_bounds__(64, 1) void lstm_fused2(
    const float* __restrict__ x,      // [B, T, 1]
    const float* __restrict__ W_ih,   // [8, 1]
    const float* __restrict__ W_hh,   // [8, 2]
    const float* __restrict__ b_ih,   // [8]
    const float* __restrict__ b_hh,   // [8]
    const float* __restrict__ W_fc,   // [4, 2]
    const float* __restrict__ b_fc,   // [4]
    float* __restrict__ out,          // [B, 4]
    int T)
{
    const int tid = blockIdx.x * 64 + threadIdx.x;
    const int e   = tid >> 1;          // batch element
    const int j   = tid & 1;           // hidden unit owned by this lane

    // Per-lane scaled weights for my unit's 4 gates (k: 0=i,1=f,2=g,3=o).
    // whm multiplies MY h, whp multiplies my PARTNER's h.
    float wihs[4], whm[4], whp[4], bbs[4];
#pragma unroll
    for (int k = 0; k < 4; ++k) {
        const int g = 2 * k + j;                         // gate row
        const float s = (k == 2) ? TANH_SCALE : SIG_SCALE;
        wihs[k] = s * W_ih[g];
        whm[k]  = s * W_hh[2 * g + j];
        whp[k]  = s * W_hh[2 * g + (j ^ 1)];
        bbs[k]  = s * (b_ih[g] + b_hh[g]);
    }

    // Packed views for v_pk_fma_f32 on the pre-activation math.
    f32x2 wihs2[2], whm2[2], whp2[2], bbs2[2];
#pragma unroll
    for (int q = 0; q < 2; ++q) {
        wihs2[q] = f32x2{wihs[2*q], wihs[2*q+1]};
        whm2[q]  = f32x2{whm[2*q],  whm[2*q+1]};
        whp2[q]  = f32x2{whp[2*q],  whp[2*q+1]};
        bbs2[q]  = f32x2{bbs[2*q],  bbs[2*q+1]};
    }

    float hm = 0.f;   // my unit's h
    float hp = 0.f;   // partner unit's h
    float c  = 0.f;   // my unit's c

    const float4* xv = reinterpret_cast<const float4*>(x + (size_t)e * (size_t)T);
    const int nt4 = T >> 2;

    for (int t4 = 0; t4 < nt4; ++t4) {
        const float4 xq = xv[t4];
        const float xs[4] = {xq.x, xq.y, xq.z, xq.w};

        // h-independent x-terms for 4 timesteps (packed fma).
        f32x2 xterm[4][2];
#pragma unroll
        for (int u = 0; u < 4; ++u) {
            const f32x2 xu = f32x2{xs[u], xs[u]};
#pragma unroll
            for (int q = 0; q < 2; ++q)
                xterm[u][q] = __builtin_elementwise_fma(xu, wihs2[q], bbs2[q]);
        }

#pragma unroll
        for (int u = 0; u < 4; ++u) {
            const f32x2 hmv = f32x2{hm, hm};
            const f32x2 hpv = f32x2{hp, hp};
            const f32x2 pre01 = __builtin_elementwise_fma(
                whm2[0], hmv, __builtin_elementwise_fma(whp2[0], hpv, xterm[u][0]));
            const f32x2 pre23 = __builtin_elementwise_fma(
                whm2[1], hmv, __builtin_elementwise_fma(whp2[1], hpv, xterm[u][1]));

            const float Ei = fast_exp2(pre01.x);
            const float Ef = fast_exp2(pre01.y);
            const float Eg = fast_exp2(pre23.x);
            const float Eo = fast_exp2(pre23.y);

            const float F   = 1.f + Ef;
            const float Gp  = 1.f + Eg;
            const float P   = fmaf(Ei, Gp, Gp);            // (1+Ei)(1+Eg)
            const float GmF = fmaf(Eg, F, -F);             // (Eg-1)(1+Ef)
            const float num = fmaf(c, P, GmF);
            const float den = F * P;
            c = num * fast_rcp(den);

            const float a  = __builtin_amdgcn_fmed3f(TANH_SCALE * c, -30.f, 30.f);
            const float Ec = fast_exp2(a);
            const float dh = (1.f + Eo) * (Ec + 1.f);
            const float r  = fast_rcp(dh);
            hm = fmaf(Ec, r, -r);                          // tanh(c)*sigmoid(o)

            hp = __shfl_xor(hm, 1, 64);                    // quad_perm DPP swap
        }
    }

    // Final FC: out[e,:] = h @ W_fc^T + b_fc.  Even lane -> classes 0,1;
    // odd lane -> classes 2,3. Lane pair writes one contiguous 16B row.
    const float h0 = j ? hp : hm;
    const float h1 = j ? hm : hp;
    const int   c0 = 2 * j;
    const float o0 = fmaf(W_fc[2*c0+0], h0, fmaf(W_fc[2*c0+1], h1, b_fc[c0]));
    const float o1 = fmaf(W_fc[2*c0+2], h0, fmaf(W_fc[2*c0+3], h1, b_fc[c0+1]));
    float2 r2; r2.x = o0; r2.y = o1;
    reinterpret_cast<float2*>(out)[e * 2 + j] = r2;
}

extern "C" void kernel_launch(void* const* d_in, const int* in_sizes, int n_in,
                              void* d_out, int out_size, void* d_ws, size_t ws_size,
                              hipStream_t stream) {
    const float* x    = (const float*)d_in[0];
    const float* W_ih = (const float*)d_in[1];
    const float* W_hh = (const float*)d_in[2];
    const float* b_ih = (const float*)d_in[3];
    const float* b_hh = (const float*)d_in[4];
    const float* W_fc = (const float*)d_in[5];
    const float* b_fc = (const float*)d_in[6];
    float* out = (float*)d_out;

    const int T = 1024;
    const int B = in_sizes[0] / T;   // I == 1

    dim3 block(64);
    dim3 grid((B * 2) / 64);         // 2 lanes/element -> 512 waves, 2 waves/CU
    lstm_fused2<<<grid, block, 0, stream>>>(x, W_ih, W_hh, b_ih, b_hh, W_fc, b_fc, out, T);
}